// Round 2
// baseline (1034.415 us; speedup 1.0000x reference)
//
#include <hip/hip_runtime.h>

typedef unsigned short u16;
typedef __attribute__((ext_vector_type(8))) short bf16x8;   // 8 bf16 = 4 VGPRs (MFMA A/B frag)
typedef __attribute__((ext_vector_type(4))) short bf16x4;
typedef __attribute__((ext_vector_type(4))) float f32x4;    // MFMA C/D frag

__device__ __forceinline__ float bf2f(u16 u){ union { unsigned int i; float f; } v; v.i = ((unsigned int)u) << 16; return v.f; }
__device__ __forceinline__ u16 f2bf(float f){ union { float f; unsigned int i; } v; v.f = f; unsigned int r = v.i + 0x7fffu + ((v.i >> 16) & 1u); return (u16)(r >> 16); }

#define MFMA(a,b,c) __builtin_amdgcn_mfma_f32_16x16x32_bf16((a),(b),(c),0,0,0)

// ---------------- Kernel 1: GroupNorm stats (mean, rstd) per (b, group) ----------------
// x layout f32 (B=16, C=512, L=4096); group = 16 channels = contiguous 65536 elems.
__global__ __launch_bounds__(256) void k_gn_stats(const float* __restrict__ x, float* __restrict__ stats){
  const int bg = blockIdx.x;                       // 0..511
  const float4* p = (const float4*)(x + (size_t)bg * 65536);
  const int tid = threadIdx.x;
  float s = 0.f, sq = 0.f;
  for (int i = 0; i < 64; ++i){
    float4 v = p[tid + i*256];
    s += v.x + v.y + v.z + v.w;
    sq += v.x*v.x + v.y*v.y + v.z*v.z + v.w*v.w;
  }
#pragma unroll
  for (int d = 32; d > 0; d >>= 1){ s += __shfl_down(s, d, 64); sq += __shfl_down(sq, d, 64); }
  __shared__ float ls[4], lq[4];
  if ((tid & 63) == 0){ ls[tid>>6] = s; lq[tid>>6] = sq; }
  __syncthreads();
  if (tid == 0){
    float S = ls[0]+ls[1]+ls[2]+ls[3];
    float Q = lq[0]+lq[1]+lq[2]+lq[3];
    float mean = S * (1.f/65536.f);
    float var  = Q * (1.f/65536.f) - mean*mean;
    stats[bg*2]   = mean;
    stats[bg*2+1] = rsqrtf(var + 1e-5f);
  }
}

// ---------------- Kernel 1b: convert f32 weights -> bf16 (w_qkv then w_proj, packed) ----------------
__global__ __launch_bounds__(256) void k_conv_w(const float* __restrict__ wq, const float* __restrict__ wp,
                                                u16* __restrict__ wout){
  const int base = (blockIdx.x*256 + threadIdx.x) * 4;       // 1024 blocks -> 1,048,576 elems
  float4 v;
  if (base < 786432) v = *(const float4*)(wq + base);
  else               v = *(const float4*)(wp + (base - 786432));
  bf16x4 o;
  o[0] = (short)f2bf(v.x); o[1] = (short)f2bf(v.y); o[2] = (short)f2bf(v.z); o[3] = (short)f2bf(v.w);
  *(bf16x4*)(wout + base) = o;
}

// ---------------- Kernel 2: GN affine + transpose -> Xnt[b][l][c] (bf16) ----------------
__global__ __launch_bounds__(256) void k_gn_t(const float* __restrict__ x, const float* __restrict__ stats,
                                              const float* __restrict__ gamma, const float* __restrict__ beta,
                                              u16* __restrict__ xnt){
  __shared__ u16 tile[64*72];                      // [c][l], stride 72
  const int l0 = blockIdx.x*64, c0 = blockIdx.y*64, b = blockIdx.z;
  const int tid = threadIdx.x;
#pragma unroll
  for (int i = 0; i < 2; ++i){
    int v = tid + i*256; int cc = v >> 3, seg = v & 7;
    int c = c0 + cc;
    float mu = stats[(b*32 + (c>>4))*2], rs = stats[(b*32 + (c>>4))*2 + 1];
    float ga = gamma[c] * rs;
    float be = beta[c] - mu * ga;                  // (x-mu)*rs*g + b = x*ga + be
    const float* px = x + ((size_t)(b*512 + c))*4096 + l0 + seg*8;
    float4 a0 = *(const float4*)px;
    float4 a1 = *(const float4*)(px + 4);
    bf16x8 ov;
    ov[0]=(short)f2bf(a0.x*ga+be); ov[1]=(short)f2bf(a0.y*ga+be);
    ov[2]=(short)f2bf(a0.z*ga+be); ov[3]=(short)f2bf(a0.w*ga+be);
    ov[4]=(short)f2bf(a1.x*ga+be); ov[5]=(short)f2bf(a1.y*ga+be);
    ov[6]=(short)f2bf(a1.z*ga+be); ov[7]=(short)f2bf(a1.w*ga+be);
    *(bf16x8*)&tile[cc*72 + seg*8] = ov;
  }
  __syncthreads();
#pragma unroll
  for (int i = 0; i < 2; ++i){
    int v = tid + i*256; int ll = v >> 3, seg = v & 7;
    bf16x8 ov;
#pragma unroll
    for (int j = 0; j < 8; ++j) ov[j] = (short)tile[(seg*8 + j)*72 + ll];
    *(bf16x8*)(xnt + ((size_t)(b*4096 + l0 + ll))*512 + c0 + seg*8) = ov;
  }
}

// ---------------- Kernel 3: QKV GEMM  D[m=l][n=o] = sum_c Xnt[l][c] * Wqkv[o][c] (+bias f32) ----------------
// Writes Qt/Kt[b][h][pos][c] (transposed via LDS bounce) and Vh[b][h][c][pos]. All bf16.
__global__ __launch_bounds__(256,2) void k_qkv(const u16* __restrict__ xnt, const u16* __restrict__ wq,
                                               const float* __restrict__ bq,
                                               u16* __restrict__ Qt, u16* __restrict__ Kt, u16* __restrict__ Vh){
  __shared__ u16 sB[128*136];
  const int l0 = blockIdx.x*128, o0 = blockIdx.y*128, b = blockIdx.z;
  const int tid = threadIdx.x, wv = tid>>6, lane = tid&63, g = lane>>4, r = lane&15;
  const int wm = wv>>1, wn = wv&1;
  const u16* arow = xnt + ((size_t)(b*4096 + l0 + wm*64 + r))*512;
  const u16* brow = wq  + ((size_t)(o0 + wn*64 + r))*512;
  f32x4 acc[4][4];
#pragma unroll
  for (int mt = 0; mt < 4; ++mt)
#pragma unroll
    for (int nt = 0; nt < 4; ++nt) acc[mt][nt] = (f32x4){0.f,0.f,0.f,0.f};
  for (int c0 = 0; c0 < 512; c0 += 32){
    const int co = c0 + g*8;
    bf16x8 a[4], bb[4];
#pragma unroll
    for (int mt = 0; mt < 4; ++mt) a[mt] = *(const bf16x8*)(arow + (size_t)mt*16*512 + co);
#pragma unroll
    for (int nt = 0; nt < 4; ++nt) bb[nt] = *(const bf16x8*)(brow + (size_t)nt*16*512 + co);
#pragma unroll
    for (int mt = 0; mt < 4; ++mt)
#pragma unroll
      for (int nt = 0; nt < 4; ++nt) acc[mt][nt] = MFMA(a[mt], bb[nt], acc[mt][nt]);
  }
  const int t   = blockIdx.y >> 2;                 // 0=Q 1=K 2=V
  const int cp0 = (blockIdx.y & 3)*128;            // c' base within tensor
  const int h   = blockIdx.x >> 2;                 // head = l0/512
  const int lh0 = (blockIdx.x & 3)*128;            // pos base within head
#pragma unroll
  for (int nt = 0; nt < 4; ++nt){
    const int ol = wn*64 + nt*16 + r;              // o local (= c')
    const float bi = bq[o0 + ol];
#pragma unroll
    for (int mt = 0; mt < 4; ++mt){
      const int ll = wm*64 + mt*16 + g*4;          // l local (D rows, 4 consecutive)
      if (t == 2){                                 // V: LDS [o][l]
        bf16x4 pk;
#pragma unroll
        for (int rr = 0; rr < 4; ++rr) pk[rr] = (short)f2bf(acc[mt][nt][rr] + bi);
        *(bf16x4*)&sB[ol*136 + ll] = pk;
      } else {                                     // Q/K: LDS [l][o] (transpose)
#pragma unroll
        for (int rr = 0; rr < 4; ++rr) sB[(ll + rr)*136 + ol] = f2bf(acc[mt][nt][rr] + bi);
      }
    }
  }
  __syncthreads();
  const size_t bh = (size_t)(b*8 + h);
  u16* dst = (t == 0) ? Qt : Kt;
#pragma unroll
  for (int i = 0; i < 8; ++i){
    int v = tid + i*256; int row = v >> 4, seg = v & 15;
    bf16x8 d = *(const bf16x8*)&sB[row*136 + seg*8];
    if (t == 2){
      *(bf16x8*)(Vh + (bh*512 + cp0 + row)*512 + lh0 + seg*8) = d;      // Vh[b][h][c'][pos]
    } else {
      *(bf16x8*)(dst + (bh*512 + lh0 + row)*512 + cp0 + seg*8) = d;     // Qt/Kt[b][h][pos][c']
    }
  }
}

// ---------------- Kernel 4: fused attention per (b, h, q-tile of 32) ----------------
// At aliases Qt IN PLACE: block (b,h,q0) reads only Q rows [q0,q0+32) and overwrites exactly
// those rows at the very end (At[b][l=h*512+q0+i][c] has the same linear offset as Qt[b][h][q0+i][c]).
__global__ __launch_bounds__(256,2) void k_attn(const u16* Qt, const u16* Kt,
                                                const u16* Vh, u16* At){
  __shared__ u16 sP[32*512];                       // P (bf16, swizzled), reused as At bounce
  __shared__ float sRed[128];                      // cross-wave softmax scratch
  const int q0 = blockIdx.x * 32;
  const int h = blockIdx.y, b = blockIdx.z;
  const int bh = b*8 + h;
  const int tid = threadIdx.x, wv = tid>>6, lane = tid&63, g = lane>>4, r = lane&15;
  const size_t base = (size_t)bh * 512 * 512;
  const u16* Qb = Qt + base; const u16* Kb = Kt + base; const u16* Vb = Vh + base;
  const int co_l = g*8;

  // ---- Phase 1: S[q 32][k 512] = sum_c Q[q][c] K[k][c]; wave wv owns k in [wv*128, wv*128+128)
  f32x4 s[2][8];
#pragma unroll
  for (int mt = 0; mt < 2; ++mt)
#pragma unroll
    for (int nt = 0; nt < 8; ++nt) s[mt][nt] = (f32x4){0.f,0.f,0.f,0.f};
  for (int c0 = 0; c0 < 512; c0 += 32){
    bf16x8 a0 = *(const bf16x8*)(Qb + (size_t)(q0      + r)*512 + c0 + co_l);
    bf16x8 a1 = *(const bf16x8*)(Qb + (size_t)(q0 + 16 + r)*512 + c0 + co_l);
    bf16x8 kb[8];
#pragma unroll
    for (int nt = 0; nt < 8; ++nt) kb[nt] = *(const bf16x8*)(Kb + (size_t)(wv*128 + nt*16 + r)*512 + c0 + co_l);
#pragma unroll
    for (int nt = 0; nt < 8; ++nt){ s[0][nt] = MFMA(a0, kb[nt], s[0][nt]); s[1][nt] = MFMA(a1, kb[nt], s[1][nt]); }
  }
  // scale = 1/sqrt(64)
#pragma unroll
  for (int mt = 0; mt < 2; ++mt)
#pragma unroll
    for (int nt = 0; nt < 8; ++nt)
#pragma unroll
      for (int rr = 0; rr < 4; ++rr) s[mt][nt][rr] *= 0.125f;

  // ---- softmax over k (D layout: q = mt*16 + g*4 + rr, k = wv*128 + nt*16 + r)
  float mx[2][4];
#pragma unroll
  for (int mt = 0; mt < 2; ++mt)
#pragma unroll
    for (int rr = 0; rr < 4; ++rr){
      float m = s[mt][0][rr];
#pragma unroll
      for (int nt = 1; nt < 8; ++nt) m = fmaxf(m, s[mt][nt][rr]);
      m = fmaxf(m, __shfl_xor(m, 1, 64)); m = fmaxf(m, __shfl_xor(m, 2, 64));
      m = fmaxf(m, __shfl_xor(m, 4, 64)); m = fmaxf(m, __shfl_xor(m, 8, 64));
      mx[mt][rr] = m;
    }
  if (r == 0){
#pragma unroll
    for (int mt = 0; mt < 2; ++mt)
#pragma unroll
      for (int rr = 0; rr < 4; ++rr) sRed[wv*32 + mt*16 + g*4 + rr] = mx[mt][rr];
  }
  __syncthreads();
#pragma unroll
  for (int mt = 0; mt < 2; ++mt)
#pragma unroll
    for (int rr = 0; rr < 4; ++rr){
      int q = mt*16 + g*4 + rr;
      mx[mt][rr] = fmaxf(fmaxf(sRed[q], sRed[32+q]), fmaxf(sRed[64+q], sRed[96+q]));
    }
  __syncthreads();
  float sm[2][4];
#pragma unroll
  for (int mt = 0; mt < 2; ++mt)
#pragma unroll
    for (int rr = 0; rr < 4; ++rr){
      float t = 0.f;
#pragma unroll
      for (int nt = 0; nt < 8; ++nt){
        float e = __expf(s[mt][nt][rr] - mx[mt][rr]);
        s[mt][nt][rr] = e; t += e;
      }
      t += __shfl_xor(t, 1, 64); t += __shfl_xor(t, 2, 64);
      t += __shfl_xor(t, 4, 64); t += __shfl_xor(t, 8, 64);
      sm[mt][rr] = t;
    }
  if (r == 0){
#pragma unroll
    for (int mt = 0; mt < 2; ++mt)
#pragma unroll
      for (int rr = 0; rr < 4; ++rr) sRed[wv*32 + mt*16 + g*4 + rr] = sm[mt][rr];
  }
  __syncthreads();
  float inv[2][4];
#pragma unroll
  for (int mt = 0; mt < 2; ++mt)
#pragma unroll
    for (int rr = 0; rr < 4; ++rr){
      int q = mt*16 + g*4 + rr;
      inv[mt][rr] = 1.f / (sRed[q] + sRed[32+q] + sRed[64+q] + sRed[96+q]);
    }
  // write P (bf16) to LDS, XOR-swizzled by q&7 on 8-elem chunks
#pragma unroll
  for (int mt = 0; mt < 2; ++mt)
#pragma unroll
    for (int nt = 0; nt < 8; ++nt)
#pragma unroll
      for (int rr = 0; rr < 4; ++rr){
        int q = mt*16 + g*4 + rr;
        int k = wv*128 + nt*16 + r;
        sP[q*512 + (((k>>3) ^ (q&7))<<3) + (k&7)] = f2bf(s[mt][nt][rr] * inv[mt][rr]);
      }
  __syncthreads();

  // ---- Phase 2: A[c 512][q 32] = sum_k V[c][k] P[q][k]; wave wv owns c in [wv*128, ...)
  f32x4 o2[8][2];
#pragma unroll
  for (int mt = 0; mt < 8; ++mt)
#pragma unroll
    for (int nt = 0; nt < 2; ++nt) o2[mt][nt] = (f32x4){0.f,0.f,0.f,0.f};
  for (int kk = 0; kk < 16; ++kk){
    const int k0 = kk*32;
    bf16x8 av[8];
#pragma unroll
    for (int mt = 0; mt < 8; ++mt) av[mt] = *(const bf16x8*)(Vb + (size_t)(wv*128 + mt*16 + r)*512 + k0 + co_l);
    bf16x8 pp[2];
#pragma unroll
    for (int nt = 0; nt < 2; ++nt){
      int q = nt*16 + r;
      int ch = (kk*4 + g) ^ (q & 7);
      pp[nt] = *(const bf16x8*)&sP[q*512 + ch*8];
    }
#pragma unroll
    for (int mt = 0; mt < 8; ++mt)
#pragma unroll
      for (int nt = 0; nt < 2; ++nt) o2[mt][nt] = MFMA(av[mt], pp[nt], o2[mt][nt]);
  }
  __syncthreads();                                  // all P reads done; reuse sP as At bounce [q][c]
#pragma unroll
  for (int mt = 0; mt < 8; ++mt)
#pragma unroll
    for (int nt = 0; nt < 2; ++nt){
      int qc = nt*16 + r;                           // D col = q
      int cl = wv*128 + mt*16 + g*4;                // D rows = c (4 consecutive)
      bf16x4 pk;
#pragma unroll
      for (int rr = 0; rr < 4; ++rr) pk[rr] = (short)f2bf(o2[mt][nt][rr]);
      *(bf16x4*)&sP[qc*512 + cl] = pk;
    }
  __syncthreads();
  u16* Ab = At + ((size_t)(b*4096 + h*512 + q0))*512;   // same linear range as this block's Q rows
#pragma unroll
  for (int i = 0; i < 8; ++i){
    int v = tid + i*256; int row = v >> 6, seg = v & 63;
    *(bf16x8*)(Ab + (size_t)row*512 + seg*8) = *(const bf16x8*)&sP[row*512 + seg*8];
  }
}

// ---------------- Kernel 5: proj GEMM + f32 residual -> f32 out ----------------
__global__ __launch_bounds__(256,2) void k_proj(const u16* __restrict__ At, const u16* __restrict__ wp,
                                                const float* __restrict__ bpr, const float* __restrict__ x,
                                                float* __restrict__ out){
  __shared__ u16 sB[128*136];
  const int l0 = blockIdx.x*128, o0 = blockIdx.y*128, b = blockIdx.z;
  const int tid = threadIdx.x, wv = tid>>6, lane = tid&63, g = lane>>4, r = lane&15;
  const int wm = wv>>1, wn = wv&1;
  const u16* arow = At + ((size_t)(b*4096 + l0 + wm*64 + r))*512;
  const u16* brow = wp + ((size_t)(o0 + wn*64 + r))*512;
  f32x4 acc[4][4];
#pragma unroll
  for (int mt = 0; mt < 4; ++mt)
#pragma unroll
    for (int nt = 0; nt < 4; ++nt) acc[mt][nt] = (f32x4){0.f,0.f,0.f,0.f};
  for (int c0 = 0; c0 < 512; c0 += 32){
    const int co = c0 + g*8;
    bf16x8 a[4], bb[4];
#pragma unroll
    for (int mt = 0; mt < 4; ++mt) a[mt] = *(const bf16x8*)(arow + (size_t)mt*16*512 + co);
#pragma unroll
    for (int nt = 0; nt < 4; ++nt) bb[nt] = *(const bf16x8*)(brow + (size_t)nt*16*512 + co);
#pragma unroll
    for (int mt = 0; mt < 4; ++mt)
#pragma unroll
      for (int nt = 0; nt < 4; ++nt) acc[mt][nt] = MFMA(a[mt], bb[nt], acc[mt][nt]);
  }
#pragma unroll
  for (int nt = 0; nt < 4; ++nt){
    const int ol = wn*64 + nt*16 + r;
    const float bi = bpr[o0 + ol];
#pragma unroll
    for (int mt = 0; mt < 4; ++mt){
      const int ll = wm*64 + mt*16 + g*4;
      bf16x4 pk;
#pragma unroll
      for (int rr = 0; rr < 4; ++rr) pk[rr] = (short)f2bf(acc[mt][nt][rr] + bi);
      *(bf16x4*)&sB[ol*136 + ll] = pk;              // LDS [o][l]
    }
  }
  __syncthreads();
#pragma unroll
  for (int i = 0; i < 16; ++i){
    int v = tid + i*256; int row = v >> 5, seg = v & 31;   // row=o-local 0..127, seg*4 = l-local
    bf16x4 d = *(const bf16x4*)&sB[row*136 + seg*4];
    const size_t gi = ((size_t)(b*512 + o0 + row))*4096 + l0 + seg*4;
    float4 xv = *(const float4*)(x + gi);
    float4 ov;
    ov.x = bf2f((u16)d[0]) + xv.x;
    ov.y = bf2f((u16)d[1]) + xv.y;
    ov.z = bf2f((u16)d[2]) + xv.z;
    ov.w = bf2f((u16)d[3]) + xv.w;
    *(float4*)(out + gi) = ov;
  }
}

extern "C" void kernel_launch(void* const* d_in, const int* in_sizes, int n_in,
                              void* d_out, int out_size, void* d_ws, size_t ws_size,
                              hipStream_t stream) {
  (void)in_sizes; (void)n_in; (void)out_size; (void)ws_size;
  const float* x     = (const float*)d_in[0];
  const float* gamma = (const float*)d_in[1];
  const float* beta  = (const float*)d_in[2];
  const float* wqkv  = (const float*)d_in[3];
  const float* bqkv  = (const float*)d_in[4];
  const float* wproj = (const float*)d_in[5];
  const float* bproj = (const float*)d_in[6];
  float* out = (float*)d_out;
  char* ws = (char*)d_ws;

  // ws layout (~194 MiB total):
  float* stats = (float*)ws;                        // 8 KB
  u16* W16  = (u16*)(ws + 8192);                    // wqkv16 (786432) + wproj16 (262144) = 2 MiB
  u16* Wq16 = W16;
  u16* Wp16 = W16 + 786432;
  u16* Qt = (u16*)(ws + 8192 + 2097152);            // 64 MiB  [b][h][pos][c]  (becomes At in place)
  u16* Kt = Qt + (size_t)33554432;                  // 64 MiB  [b][h][pos][c]
  u16* Vh = Kt + (size_t)33554432;                  // 64 MiB  [b][h][c][pos]
  u16* At = Qt;                                     // in-place alias (see k_attn)
  u16* Xnt = (u16*)d_out;                           // bf16 staging in d_out (dead before k_proj writes)

  k_gn_stats<<<512, 256, 0, stream>>>(x, stats);
  k_conv_w<<<1024, 256, 0, stream>>>(wqkv, wproj, W16);
  k_gn_t<<<dim3(64,8,16), 256, 0, stream>>>(x, stats, gamma, beta, Xnt);
  k_qkv<<<dim3(32,12,16), 256, 0, stream>>>(Xnt, Wq16, bqkv, Qt, Kt, Vh);
  k_attn<<<dim3(16,8,16), 256, 0, stream>>>(Qt, Kt, Vh, At);
  k_proj<<<dim3(32,4,16), 256, 0, stream>>>(At, Wp16, bproj, x, out);
}

// Round 3
// 749.635 us; speedup vs baseline: 1.3799x; 1.3799x over previous
//
#include <hip/hip_runtime.h>

typedef unsigned short u16;
typedef __attribute__((ext_vector_type(8))) short bf16x8;   // 8 bf16 = 4 VGPRs (MFMA A/B frag)
typedef __attribute__((ext_vector_type(4))) short bf16x4;
typedef __attribute__((ext_vector_type(4))) float f32x4;    // MFMA C/D frag

__device__ __forceinline__ float bf2f(u16 u){ union { unsigned int i; float f; } v; v.i = ((unsigned int)u) << 16; return v.f; }
__device__ __forceinline__ u16 f2bf(float f){ union { float f; unsigned int i; } v; v.f = f; unsigned int r = v.i + 0x7fffu + ((v.i >> 16) & 1u); return (u16)(r >> 16); }

#define MFMA(a,b,c) __builtin_amdgcn_mfma_f32_16x16x32_bf16((a),(b),(c),0,0,0)

// async global->LDS, 16B per lane. LDS dest is wave-uniform base + lane*16.
__device__ __forceinline__ void gl_lds16(const u16* g, u16* l){
  __builtin_amdgcn_global_load_lds((const __attribute__((address_space(1))) unsigned int*)g,
                                   (__attribute__((address_space(3))) unsigned int*)l, 16, 0, 0);
}

// ---------------- Kernel 1: GroupNorm stats (mean, rstd) per (b, group) ----------------
__global__ __launch_bounds__(256) void k_gn_stats(const float* __restrict__ x, float* __restrict__ stats){
  const int bg = blockIdx.x;                       // 0..511
  const float4* p = (const float4*)(x + (size_t)bg * 65536);
  const int tid = threadIdx.x;
  float s = 0.f, sq = 0.f;
  for (int i = 0; i < 64; ++i){
    float4 v = p[tid + i*256];
    s += v.x + v.y + v.z + v.w;
    sq += v.x*v.x + v.y*v.y + v.z*v.z + v.w*v.w;
  }
#pragma unroll
  for (int d = 32; d > 0; d >>= 1){ s += __shfl_down(s, d, 64); sq += __shfl_down(sq, d, 64); }
  __shared__ float ls[4], lq[4];
  if ((tid & 63) == 0){ ls[tid>>6] = s; lq[tid>>6] = sq; }
  __syncthreads();
  if (tid == 0){
    float S = ls[0]+ls[1]+ls[2]+ls[3];
    float Q = lq[0]+lq[1]+lq[2]+lq[3];
    float mean = S * (1.f/65536.f);
    float var  = Q * (1.f/65536.f) - mean*mean;
    stats[bg*2]   = mean;
    stats[bg*2+1] = rsqrtf(var + 1e-5f);
  }
}

// ---------------- Kernel 1b: convert f32 weights -> bf16 (w_qkv then w_proj, packed) ----------------
__global__ __launch_bounds__(256) void k_conv_w(const float* __restrict__ wq, const float* __restrict__ wp,
                                                u16* __restrict__ wout){
  const int base = (blockIdx.x*256 + threadIdx.x) * 4;       // 1024 blocks -> 1,048,576 elems
  float4 v;
  if (base < 786432) v = *(const float4*)(wq + base);
  else               v = *(const float4*)(wp + (base - 786432));
  bf16x4 o;
  o[0] = (short)f2bf(v.x); o[1] = (short)f2bf(v.y); o[2] = (short)f2bf(v.z); o[3] = (short)f2bf(v.w);
  *(bf16x4*)(wout + base) = o;
}

// ---------------- Kernel 2: GN affine + transpose -> Xnt[b][l][c] (bf16) ----------------
__global__ __launch_bounds__(256) void k_gn_t(const float* __restrict__ x, const float* __restrict__ stats,
                                              const float* __restrict__ gamma, const float* __restrict__ beta,
                                              u16* __restrict__ xnt){
  __shared__ u16 tile[64*72];                      // [c][l], stride 72
  const int l0 = blockIdx.x*64, c0 = blockIdx.y*64, b = blockIdx.z;
  const int tid = threadIdx.x;
#pragma unroll
  for (int i = 0; i < 2; ++i){
    int v = tid + i*256; int cc = v >> 3, seg = v & 7;
    int c = c0 + cc;
    float mu = stats[(b*32 + (c>>4))*2], rs = stats[(b*32 + (c>>4))*2 + 1];
    float ga = gamma[c] * rs;
    float be = beta[c] - mu * ga;                  // (x-mu)*rs*g + b = x*ga + be
    const float* px = x + ((size_t)(b*512 + c))*4096 + l0 + seg*8;
    float4 a0 = *(const float4*)px;
    float4 a1 = *(const float4*)(px + 4);
    bf16x8 ov;
    ov[0]=(short)f2bf(a0.x*ga+be); ov[1]=(short)f2bf(a0.y*ga+be);
    ov[2]=(short)f2bf(a0.z*ga+be); ov[3]=(short)f2bf(a0.w*ga+be);
    ov[4]=(short)f2bf(a1.x*ga+be); ov[5]=(short)f2bf(a1.y*ga+be);
    ov[6]=(short)f2bf(a1.z*ga+be); ov[7]=(short)f2bf(a1.w*ga+be);
    *(bf16x8*)&tile[cc*72 + seg*8] = ov;
  }
  __syncthreads();
#pragma unroll
  for (int i = 0; i < 2; ++i){
    int v = tid + i*256; int ll = v >> 3, seg = v & 7;
    bf16x8 ov;
#pragma unroll
    for (int j = 0; j < 8; ++j) ov[j] = (short)tile[(seg*8 + j)*72 + ll];
    *(bf16x8*)(xnt + ((size_t)(b*4096 + l0 + ll))*512 + c0 + seg*8) = ov;
  }
}

// ---------------- Kernel 3: QKV GEMM (m97-style: global_load_lds staging, swizzled LDS) ----------------
// D[m=l][n=o] = sum_c Xnt[l][c] * Wqkv[o][c] (+bias). Writes Qt/Kt[b][h][pos][c], Vh[b][h][c][pos].
// LDS tiles sA/sW: 128 rows x 64 cols bf16, stored as 16B chunks; chunk cc of row is at
// slot (row*8 + (cc ^ (row&7))) -- swizzle applied on the GLOBAL address side so the
// lane-contiguous LDS writes of global_load_lds land swizzled; ds_read_b128 is bank-balanced.
__global__ __launch_bounds__(256,2) void k_qkv(const u16* __restrict__ xnt, const u16* __restrict__ wq,
                                               const float* __restrict__ bq,
                                               u16* __restrict__ Qt, u16* __restrict__ Kt, u16* __restrict__ Vh){
  __shared__ u16 smem[17408];                      // 34816 B: sA[0:8192)+sW[8192:16384); epilogue reuses as 128x136
  u16* sA = smem;
  u16* sW = smem + 8192;
  const int l0 = blockIdx.x*128, o0 = blockIdx.y*128, b = blockIdx.z;
  const int tid = threadIdx.x, wv = tid>>6, lane = tid&63, g = lane>>4, r = lane&15;
  const int wm = wv>>1, wn = wv&1;
  const u16* Ab = xnt + ((size_t)(b*4096 + l0))*512;
  const u16* Wb = wq  + (size_t)o0*512;
  // staging: chunk slot s = wv*256 + j*64 + lane; row = s>>3; global cc = (s&7) ^ (row&7)
  int srow[4], scol[4];
#pragma unroll
  for (int j = 0; j < 4; ++j){
    int s = wv*256 + j*64 + lane;
    srow[j] = s >> 3;
    scol[j] = ((s & 7) ^ (srow[j] & 7)) * 8;
  }
  f32x4 acc[4][4];
#pragma unroll
  for (int mt = 0; mt < 4; ++mt)
#pragma unroll
    for (int nt = 0; nt < 4; ++nt) acc[mt][nt] = (f32x4){0.f,0.f,0.f,0.f};

  const int key = r & 7;
  for (int c0 = 0; c0 < 512; c0 += 64){
    __syncthreads();                               // prev tile's reads done
#pragma unroll
    for (int j = 0; j < 4; ++j){
      u16* ldst = &smem[(wv*256 + j*64)*8];        // wave-uniform
      gl_lds16(Ab + (size_t)srow[j]*512 + c0 + scol[j], ldst);
      gl_lds16(Wb + (size_t)srow[j]*512 + c0 + scol[j], ldst + 8192);
    }
    __syncthreads();                               // staged data visible
#pragma unroll
    for (int half = 0; half < 2; ++half){
      bf16x8 a[4], w[4];
#pragma unroll
      for (int mt = 0; mt < 4; ++mt){ int R = wm*64 + mt*16 + r; a[mt] = *(const bf16x8*)&sA[(R*8 + ((half*4+g) ^ key))*8]; }
#pragma unroll
      for (int nt = 0; nt < 4; ++nt){ int R = wn*64 + nt*16 + r; w[nt] = *(const bf16x8*)&sW[(R*8 + ((half*4+g) ^ key))*8]; }
#pragma unroll
      for (int mt = 0; mt < 4; ++mt)
#pragma unroll
        for (int nt = 0; nt < 4; ++nt) acc[mt][nt] = MFMA(a[mt], w[nt], acc[mt][nt]);
    }
  }
  __syncthreads();                                 // last tile's reads done; reuse smem for epilogue
  const int t   = blockIdx.y >> 2;                 // 0=Q 1=K 2=V
  const int cp0 = (blockIdx.y & 3)*128;            // c' base within tensor
  const int h   = blockIdx.x >> 2;                 // head = l0/512
  const int lh0 = (blockIdx.x & 3)*128;            // pos base within head
#pragma unroll
  for (int nt = 0; nt < 4; ++nt){
    const int ol = wn*64 + nt*16 + r;              // o local (= c')
    const float bi = bq[o0 + ol];
#pragma unroll
    for (int mt = 0; mt < 4; ++mt){
      const int ll = wm*64 + mt*16 + g*4;          // l local (D rows, 4 consecutive)
      if (t == 2){                                 // V: LDS [o][l]
        bf16x4 pk;
#pragma unroll
        for (int rr = 0; rr < 4; ++rr) pk[rr] = (short)f2bf(acc[mt][nt][rr] + bi);
        *(bf16x4*)&smem[ol*136 + ll] = pk;
      } else {                                     // Q/K: LDS [l][o] (transpose)
#pragma unroll
        for (int rr = 0; rr < 4; ++rr) smem[(ll + rr)*136 + ol] = f2bf(acc[mt][nt][rr] + bi);
      }
    }
  }
  __syncthreads();
  const size_t bh = (size_t)(b*8 + h);
  u16* dst = (t == 0) ? Qt : Kt;
#pragma unroll
  for (int i = 0; i < 8; ++i){
    int v = tid + i*256; int row = v >> 4, seg = v & 15;
    bf16x8 d = *(const bf16x8*)&smem[row*136 + seg*8];
    if (t == 2){
      *(bf16x8*)(Vh + (bh*512 + cp0 + row)*512 + lh0 + seg*8) = d;      // Vh[b][h][c'][pos]
    } else {
      *(bf16x8*)(dst + (bh*512 + lh0 + row)*512 + cp0 + seg*8) = d;     // Qt/Kt[b][h][pos][c']
    }
  }
}

// ---------------- Kernel 4: fused attention per (b, h, q-tile of 32) ----------------
// At aliases Qt IN PLACE: block (b,h,q0) reads only Q rows [q0,q0+32) and overwrites exactly those.
__global__ __launch_bounds__(256,2) void k_attn(const u16* Qt, const u16* Kt,
                                                const u16* Vh, u16* At){
  __shared__ u16 sP[32*512];                       // P (bf16, swizzled), reused as At bounce
  __shared__ float sRed[128];                      // cross-wave softmax scratch
  const int q0 = blockIdx.x * 32;
  const int h = blockIdx.y, b = blockIdx.z;
  const int bh = b*8 + h;
  const int tid = threadIdx.x, wv = tid>>6, lane = tid&63, g = lane>>4, r = lane&15;
  const size_t base = (size_t)bh * 512 * 512;
  const u16* Qb = Qt + base; const u16* Kb = Kt + base; const u16* Vb = Vh + base;
  const int co_l = g*8;

  // ---- Phase 1: S[q 32][k 512] = sum_c Q[q][c] K[k][c]; wave wv owns k in [wv*128, wv*128+128)
  f32x4 s[2][8];
#pragma unroll
  for (int mt = 0; mt < 2; ++mt)
#pragma unroll
    for (int nt = 0; nt < 8; ++nt) s[mt][nt] = (f32x4){0.f,0.f,0.f,0.f};
  for (int c0 = 0; c0 < 512; c0 += 32){
    bf16x8 a0 = *(const bf16x8*)(Qb + (size_t)(q0      + r)*512 + c0 + co_l);
    bf16x8 a1 = *(const bf16x8*)(Qb + (size_t)(q0 + 16 + r)*512 + c0 + co_l);
    bf16x8 kb[8];
#pragma unroll
    for (int nt = 0; nt < 8; ++nt) kb[nt] = *(const bf16x8*)(Kb + (size_t)(wv*128 + nt*16 + r)*512 + c0 + co_l);
#pragma unroll
    for (int nt = 0; nt < 8; ++nt){ s[0][nt] = MFMA(a0, kb[nt], s[0][nt]); s[1][nt] = MFMA(a1, kb[nt], s[1][nt]); }
  }
#pragma unroll
  for (int mt = 0; mt < 2; ++mt)
#pragma unroll
    for (int nt = 0; nt < 8; ++nt)
#pragma unroll
      for (int rr = 0; rr < 4; ++rr) s[mt][nt][rr] *= 0.125f;

  // ---- softmax over k (D layout: q = mt*16 + g*4 + rr, k = wv*128 + nt*16 + r)
  float mx[2][4];
#pragma unroll
  for (int mt = 0; mt < 2; ++mt)
#pragma unroll
    for (int rr = 0; rr < 4; ++rr){
      float m = s[mt][0][rr];
#pragma unroll
      for (int nt = 1; nt < 8; ++nt) m = fmaxf(m, s[mt][nt][rr]);
      m = fmaxf(m, __shfl_xor(m, 1, 64)); m = fmaxf(m, __shfl_xor(m, 2, 64));
      m = fmaxf(m, __shfl_xor(m, 4, 64)); m = fmaxf(m, __shfl_xor(m, 8, 64));
      mx[mt][rr] = m;
    }
  if (r == 0){
#pragma unroll
    for (int mt = 0; mt < 2; ++mt)
#pragma unroll
      for (int rr = 0; rr < 4; ++rr) sRed[wv*32 + mt*16 + g*4 + rr] = mx[mt][rr];
  }
  __syncthreads();
#pragma unroll
  for (int mt = 0; mt < 2; ++mt)
#pragma unroll
    for (int rr = 0; rr < 4; ++rr){
      int q = mt*16 + g*4 + rr;
      mx[mt][rr] = fmaxf(fmaxf(sRed[q], sRed[32+q]), fmaxf(sRed[64+q], sRed[96+q]));
    }
  __syncthreads();
  float sm[2][4];
#pragma unroll
  for (int mt = 0; mt < 2; ++mt)
#pragma unroll
    for (int rr = 0; rr < 4; ++rr){
      float t = 0.f;
#pragma unroll
      for (int nt = 0; nt < 8; ++nt){
        float e = __expf(s[mt][nt][rr] - mx[mt][rr]);
        s[mt][nt][rr] = e; t += e;
      }
      t += __shfl_xor(t, 1, 64); t += __shfl_xor(t, 2, 64);
      t += __shfl_xor(t, 4, 64); t += __shfl_xor(t, 8, 64);
      sm[mt][rr] = t;
    }
  if (r == 0){
#pragma unroll
    for (int mt = 0; mt < 2; ++mt)
#pragma unroll
      for (int rr = 0; rr < 4; ++rr) sRed[wv*32 + mt*16 + g*4 + rr] = sm[mt][rr];
  }
  __syncthreads();
  float inv[2][4];
#pragma unroll
  for (int mt = 0; mt < 2; ++mt)
#pragma unroll
    for (int rr = 0; rr < 4; ++rr){
      int q = mt*16 + g*4 + rr;
      inv[mt][rr] = 1.f / (sRed[q] + sRed[32+q] + sRed[64+q] + sRed[96+q]);
    }
#pragma unroll
  for (int mt = 0; mt < 2; ++mt)
#pragma unroll
    for (int nt = 0; nt < 8; ++nt)
#pragma unroll
      for (int rr = 0; rr < 4; ++rr){
        int q = mt*16 + g*4 + rr;
        int k = wv*128 + nt*16 + r;
        sP[q*512 + (((k>>3) ^ (q&7))<<3) + (k&7)] = f2bf(s[mt][nt][rr] * inv[mt][rr]);
      }
  __syncthreads();

  // ---- Phase 2: A[c 512][q 32] = sum_k V[c][k] P[q][k]; wave wv owns c in [wv*128, ...)
  f32x4 o2[8][2];
#pragma unroll
  for (int mt = 0; mt < 8; ++mt)
#pragma unroll
    for (int nt = 0; nt < 2; ++nt) o2[mt][nt] = (f32x4){0.f,0.f,0.f,0.f};
  for (int kk = 0; kk < 16; ++kk){
    const int k0 = kk*32;
    bf16x8 av[8];
#pragma unroll
    for (int mt = 0; mt < 8; ++mt) av[mt] = *(const bf16x8*)(Vb + (size_t)(wv*128 + mt*16 + r)*512 + k0 + co_l);
    bf16x8 pp[2];
#pragma unroll
    for (int nt = 0; nt < 2; ++nt){
      int q = nt*16 + r;
      int ch = (kk*4 + g) ^ (q & 7);
      pp[nt] = *(const bf16x8*)&sP[q*512 + ch*8];
    }
#pragma unroll
    for (int mt = 0; mt < 8; ++mt)
#pragma unroll
      for (int nt = 0; nt < 2; ++nt) o2[mt][nt] = MFMA(av[mt], pp[nt], o2[mt][nt]);
  }
  __syncthreads();                                  // all P reads done; reuse sP as At bounce [q][c]
#pragma unroll
  for (int mt = 0; mt < 8; ++mt)
#pragma unroll
    for (int nt = 0; nt < 2; ++nt){
      int qc = nt*16 + r;                           // D col = q
      int cl = wv*128 + mt*16 + g*4;                // D rows = c (4 consecutive)
      bf16x4 pk;
#pragma unroll
      for (int rr = 0; rr < 4; ++rr) pk[rr] = (short)f2bf(o2[mt][nt][rr]);
      *(bf16x4*)&sP[qc*512 + cl] = pk;
    }
  __syncthreads();
  u16* Ab = At + ((size_t)(b*4096 + h*512 + q0))*512;   // same linear range as this block's Q rows
#pragma unroll
  for (int i = 0; i < 8; ++i){
    int v = tid + i*256; int row = v >> 6, seg = v & 63;
    *(bf16x8*)(Ab + (size_t)row*512 + seg*8) = *(const bf16x8*)&sP[row*512 + seg*8];
  }
}

// ---------------- Kernel 5: proj GEMM (m97-style) + f32 residual -> f32 out ----------------
__global__ __launch_bounds__(256,2) void k_proj(const u16* __restrict__ At, const u16* __restrict__ wp,
                                                const float* __restrict__ bpr, const float* __restrict__ x,
                                                float* __restrict__ out){
  __shared__ u16 smem[17408];
  u16* sA = smem;
  u16* sW = smem + 8192;
  const int l0 = blockIdx.x*128, o0 = blockIdx.y*128, b = blockIdx.z;
  const int tid = threadIdx.x, wv = tid>>6, lane = tid&63, g = lane>>4, r = lane&15;
  const int wm = wv>>1, wn = wv&1;
  const u16* Ab = At + ((size_t)(b*4096 + l0))*512;
  const u16* Wb = wp + (size_t)o0*512;
  int srow[4], scol[4];
#pragma unroll
  for (int j = 0; j < 4; ++j){
    int s = wv*256 + j*64 + lane;
    srow[j] = s >> 3;
    scol[j] = ((s & 7) ^ (srow[j] & 7)) * 8;
  }
  f32x4 acc[4][4];
#pragma unroll
  for (int mt = 0; mt < 4; ++mt)
#pragma unroll
    for (int nt = 0; nt < 4; ++nt) acc[mt][nt] = (f32x4){0.f,0.f,0.f,0.f};
  const int key = r & 7;
  for (int c0 = 0; c0 < 512; c0 += 64){
    __syncthreads();
#pragma unroll
    for (int j = 0; j < 4; ++j){
      u16* ldst = &smem[(wv*256 + j*64)*8];
      gl_lds16(Ab + (size_t)srow[j]*512 + c0 + scol[j], ldst);
      gl_lds16(Wb + (size_t)srow[j]*512 + c0 + scol[j], ldst + 8192);
    }
    __syncthreads();
#pragma unroll
    for (int half = 0; half < 2; ++half){
      bf16x8 a[4], w[4];
#pragma unroll
      for (int mt = 0; mt < 4; ++mt){ int R = wm*64 + mt*16 + r; a[mt] = *(const bf16x8*)&sA[(R*8 + ((half*4+g) ^ key))*8]; }
#pragma unroll
      for (int nt = 0; nt < 4; ++nt){ int R = wn*64 + nt*16 + r; w[nt] = *(const bf16x8*)&sW[(R*8 + ((half*4+g) ^ key))*8]; }
#pragma unroll
      for (int mt = 0; mt < 4; ++mt)
#pragma unroll
        for (int nt = 0; nt < 4; ++nt) acc[mt][nt] = MFMA(a[mt], w[nt], acc[mt][nt]);
    }
  }
  __syncthreads();
#pragma unroll
  for (int nt = 0; nt < 4; ++nt){
    const int ol = wn*64 + nt*16 + r;
    const float bi = bpr[o0 + ol];
#pragma unroll
    for (int mt = 0; mt < 4; ++mt){
      const int ll = wm*64 + mt*16 + g*4;
      bf16x4 pk;
#pragma unroll
      for (int rr = 0; rr < 4; ++rr) pk[rr] = (short)f2bf(acc[mt][nt][rr] + bi);
      *(bf16x4*)&smem[ol*136 + ll] = pk;            // LDS [o][l]
    }
  }
  __syncthreads();
#pragma unroll
  for (int i = 0; i < 16; ++i){
    int v = tid + i*256; int row = v >> 5, seg = v & 31;   // row=o-local 0..127, seg*4 = l-local
    bf16x4 d = *(const bf16x4*)&smem[row*136 + seg*4];
    const size_t gi = ((size_t)(b*512 + o0 + row))*4096 + l0 + seg*4;
    float4 xv = *(const float4*)(x + gi);
    float4 ov;
    ov.x = bf2f((u16)d[0]) + xv.x;
    ov.y = bf2f((u16)d[1]) + xv.y;
    ov.z = bf2f((u16)d[2]) + xv.z;
    ov.w = bf2f((u16)d[3]) + xv.w;
    *(float4*)(out + gi) = ov;
  }
}

extern "C" void kernel_launch(void* const* d_in, const int* in_sizes, int n_in,
                              void* d_out, int out_size, void* d_ws, size_t ws_size,
                              hipStream_t stream) {
  (void)in_sizes; (void)n_in; (void)out_size; (void)ws_size;
  const float* x     = (const float*)d_in[0];
  const float* gamma = (const float*)d_in[1];
  const float* beta  = (const float*)d_in[2];
  const float* wqkv  = (const float*)d_in[3];
  const float* bqkv  = (const float*)d_in[4];
  const float* wproj = (const float*)d_in[5];
  const float* bproj = (const float*)d_in[6];
  float* out = (float*)d_out;
  char* ws = (char*)d_ws;

  float* stats = (float*)ws;                        // 8 KB
  u16* W16  = (u16*)(ws + 8192);                    // wqkv16 (786432) + wproj16 (262144)
  u16* Wq16 = W16;
  u16* Wp16 = W16 + 786432;
  u16* Qt = (u16*)(ws + 8192 + 2097152);            // 64 MiB  [b][h][pos][c]  (becomes At in place)
  u16* Kt = Qt + (size_t)33554432;                  // 64 MiB  [b][h][pos][c]
  u16* Vh = Kt + (size_t)33554432;                  // 64 MiB  [b][h][c][pos]
  u16* At = Qt;                                     // in-place alias (see k_attn)
  u16* Xnt = (u16*)d_out;                           // bf16 staging in d_out (dead before k_proj writes)

  k_gn_stats<<<512, 256, 0, stream>>>(x, stats);
  k_conv_w<<<1024, 256, 0, stream>>>(wqkv, wproj, W16);
  k_gn_t<<<dim3(64,8,16), 256, 0, stream>>>(x, stats, gamma, beta, Xnt);
  k_qkv<<<dim3(32,12,16), 256, 0, stream>>>(Xnt, Wq16, bqkv, Qt, Kt, Vh);
  k_attn<<<dim3(16,8,16), 256, 0, stream>>>(Qt, Kt, Vh, At);
  k_proj<<<dim3(32,4,16), 256, 0, stream>>>(At, Wp16, bproj, x, out);
}